// Round 1
// 1224.416 us; speedup vs baseline: 1.0824x; 1.0824x over previous
//
#include <hip/hip_runtime.h>

// ParallelLlamaAttention on MI355X (gfx950).
// R5: (a) GEMMs upgraded to m97 structure: bf16 pre-convert pass + global_load_lds
//     width=16 staging (ladder: 517->874 TF). Old fp32-source GEMM kept as fallback
//     when ws_size < 128MB. (b) attn LDS: sV and sP lifetimes are disjoint
//     (staging->transpose vs compute) -> aliased into one buffer; 71680->54272 B,
//     2 -> 3 blocks/CU for the latency-bound attention kernel.
// ws layout (fast path, 128MB total):
//   qkv  bf16 [4096][6144] @ 0        (50.3MB)  live: gemm1 .. attn
//   hb   bf16 [4096][4096] @ 50.3MB   (33.6MB)  live: conv .. gemm1
//   aout bf16 [4096][4096] @ 50.3MB   (33.6MB)  live: attn .. gemm2 (reuses hb)
//   wqb  bf16 [6144][4096] @ 83.9MB   (50.3MB)  live: conv .. gemm1
//   wob  bf16 [4096][4096] @ 83.9MB   (33.6MB)  live: conv2 .. gemm2 (reuses wqb)

typedef unsigned short u16;
typedef __attribute__((ext_vector_type(8))) short bh8;   // 8 bf16 = 4 VGPRs
typedef __attribute__((ext_vector_type(4))) float f4;    // MFMA 16x16 accumulator

#define MFMA16(a, b, c) __builtin_amdgcn_mfma_f32_16x16x32_bf16(a, b, c, 0, 0, 0)

__device__ __forceinline__ u16 f2bf(float f) {  // RNE f32 -> bf16
  union { float f; unsigned u; } v; v.f = f;
  unsigned r = v.u + 0x7fffu + ((v.u >> 16) & 1u);
  return (u16)(r >> 16);
}
__device__ __forceinline__ float bf2f(u16 h) {
  union { unsigned u; float f; } v; v.u = ((unsigned)h) << 16;
  return v.f;
}
__device__ __forceinline__ float rmax16(float v) {  // reduce over 16-lane group
  v = fmaxf(v, __shfl_xor(v, 1, 64));
  v = fmaxf(v, __shfl_xor(v, 2, 64));
  v = fmaxf(v, __shfl_xor(v, 4, 64));
  v = fmaxf(v, __shfl_xor(v, 8, 64));
  return v;
}
__device__ __forceinline__ float rsum16(float v) {
  v += __shfl_xor(v, 1, 64);
  v += __shfl_xor(v, 2, 64);
  v += __shfl_xor(v, 4, 64);
  v += __shfl_xor(v, 8, 64);
  return v;
}

// load 8 contiguous elements as bf16x8, converting if the source is fp32
__device__ __forceinline__ bh8 load8_cvt(const float* p) {
  float4 lo = *(const float4*)p;
  float4 hi = *(const float4*)(p + 4);
  bh8 r;
  r[0] = (short)f2bf(lo.x); r[1] = (short)f2bf(lo.y);
  r[2] = (short)f2bf(lo.z); r[3] = (short)f2bf(lo.w);
  r[4] = (short)f2bf(hi.x); r[5] = (short)f2bf(hi.y);
  r[6] = (short)f2bf(hi.z); r[7] = (short)f2bf(hi.w);
  return r;
}
__device__ __forceinline__ bh8 load8_cvt(const u16* p) {
  return *(const bh8*)p;
}
__device__ __forceinline__ void store_c(u16* C, size_t idx, float v) { C[idx] = f2bf(v); }
__device__ __forceinline__ void store_c(float* C, size_t idx, float v) { C[idx] = v; }

// async global(16B/lane) -> LDS. LDS dest = wave-uniform base + lane*16.
__device__ __forceinline__ void gload16(const u16* g, u16* l) {
  __builtin_amdgcn_global_load_lds(
      (const __attribute__((address_space(1))) void*)g,
      (__attribute__((address_space(3))) void*)l, 16, 0, 0);
}

// ---------------- elementwise fp32 -> bf16 (vectorized, grid-stride) ----------------
__global__ __launch_bounds__(256) void f32_to_bf16(const float* __restrict__ in,
                                                   u16* __restrict__ out, int n8) {
  int i = blockIdx.x * 256 + threadIdx.x;
  const int stride = gridDim.x * 256;
  for (; i < n8; i += stride) {
    bh8 v = load8_cvt(in + (size_t)i * 8);
    *(bh8*)(out + (size_t)i * 8) = v;
  }
}

// ---------------- GEMM (m97): C[M,N] = A[M,K] * B[N,K]^T, bf16 in, fp32 acc ----------
// 128x128 tile, BK=32, 4 waves 2x2, 4x4 16x16 acc/wave. Staging via global_load_lds
// width=16: per wave 2 chunks of A + 2 of B per K-step (chunk = 1KB = 16 rows x 32k).
template <typename TC>
__global__ __launch_bounds__(256) void gemm_bt_lds(const u16* __restrict__ A,
                                                   const u16* __restrict__ B,
                                                   TC* __restrict__ C,
                                                   int M, int N, int K) {
  __shared__ u16 sA[128 * 32];
  __shared__ u16 sB[128 * 32];
  const int tid = threadIdx.x;
  const int wave = tid >> 6, lane = tid & 63;
  const int quad = lane >> 4, l16 = lane & 15;
  const int bm = blockIdx.y * 128, bn = blockIdx.x * 128;
  const int wm = (wave & 1) * 64, wn = (wave >> 1) * 64;

  f4 zero4 = {0.f, 0.f, 0.f, 0.f};
  f4 acc[4][4];
#pragma unroll
  for (int i = 0; i < 4; i++)
#pragma unroll
    for (int j = 0; j < 4; j++) acc[i][j] = zero4;

  // chunk ch covers LDS rows [ch*16, ch*16+16); lane l -> row ch*16 + l/4, k (l%4)*8
  const int ch0 = wave * 2, ch1 = ch0 + 1;
  const int rr = lane >> 2, kc = (lane & 3) * 8;
  const u16* A0 = A + (size_t)(bm + ch0 * 16 + rr) * K + kc;
  const u16* A1 = A + (size_t)(bm + ch1 * 16 + rr) * K + kc;
  const u16* B0 = B + (size_t)(bn + ch0 * 16 + rr) * K + kc;
  const u16* B1 = B + (size_t)(bn + ch1 * 16 + rr) * K + kc;
  u16* la0 = &sA[ch0 * 512];
  u16* la1 = &sA[ch1 * 512];
  u16* lb0 = &sB[ch0 * 512];
  u16* lb1 = &sB[ch1 * 512];

  for (int k0 = 0; k0 < K; k0 += 32) {
    __syncthreads();  // prior iteration's frag reads complete before overwrite
    gload16(A0 + k0, la0);
    gload16(A1 + k0, la1);
    gload16(B0 + k0, lb0);
    gload16(B1 + k0, lb1);
    __syncthreads();  // compiler drains vmcnt(0) before s_barrier -> staging visible
    bh8 aF[4], bF[4];
#pragma unroll
    for (int t = 0; t < 4; t++) {
      aF[t] = *(const bh8*)&sA[(wm + t * 16 + l16) * 32 + quad * 8];
      bF[t] = *(const bh8*)&sB[(wn + t * 16 + l16) * 32 + quad * 8];
    }
#pragma unroll
    for (int i = 0; i < 4; i++)
#pragma unroll
      for (int j = 0; j < 4; j++) acc[i][j] = MFMA16(aF[i], bF[j], acc[i][j]);
  }

  // C/D layout: row = quad*4+reg, col = l16
#pragma unroll
  for (int i = 0; i < 4; i++)
#pragma unroll
    for (int j = 0; j < 4; j++)
#pragma unroll
      for (int r = 0; r < 4; r++) {
        int row = bm + wm + i * 16 + quad * 4 + r;
        int col = bn + wn + j * 16 + l16;
        store_c(C, (size_t)row * N + col, acc[i][j][r]);
      }
}

// ---------------- fallback GEMM (fp32 sources, convert-in-staging) ----------------
template <typename TA, typename TB, typename TC>
__global__ __launch_bounds__(256) void gemm_bt(const TA* __restrict__ A,
                                               const TB* __restrict__ B,
                                               TC* __restrict__ C,
                                               int M, int N, int K) {
  __shared__ u16 sA[128 * 32];
  __shared__ u16 sB[128 * 32];
  const int tid = threadIdx.x;
  const int wave = tid >> 6, lane = tid & 63;
  const int quad = lane >> 4, l16 = lane & 15;
  const int bm = blockIdx.y * 128, bn = blockIdx.x * 128;
  const int wm = (wave & 1) * 64, wn = (wave >> 1) * 64;

  f4 zero4 = {0.f, 0.f, 0.f, 0.f};
  f4 acc[4][4];
#pragma unroll
  for (int i = 0; i < 4; i++)
#pragma unroll
    for (int j = 0; j < 4; j++) acc[i][j] = zero4;

  const int c0 = tid, c1 = 256 + tid;
  const TA* Ar0 = A + (size_t)(bm + (c0 >> 2)) * K + (c0 & 3) * 8;
  const TA* Ar1 = A + (size_t)(bm + (c1 >> 2)) * K + (c1 & 3) * 8;
  const TB* Br0 = B + (size_t)(bn + (c0 >> 2)) * K + (c0 & 3) * 8;
  const TB* Br1 = B + (size_t)(bn + (c1 >> 2)) * K + (c1 & 3) * 8;

  for (int k0 = 0; k0 < K; k0 += 32) {
    bh8 a0 = load8_cvt(Ar0 + k0);
    bh8 a1 = load8_cvt(Ar1 + k0);
    bh8 b0 = load8_cvt(Br0 + k0);
    bh8 b1 = load8_cvt(Br1 + k0);
    __syncthreads();
    *(bh8*)&sA[c0 * 8] = a0;
    *(bh8*)&sA[c1 * 8] = a1;
    *(bh8*)&sB[c0 * 8] = b0;
    *(bh8*)&sB[c1 * 8] = b1;
    __syncthreads();
    bh8 aF[4], bF[4];
#pragma unroll
    for (int t = 0; t < 4; t++) {
      aF[t] = *(const bh8*)&sA[(wm + t * 16 + l16) * 32 + quad * 8];
      bF[t] = *(const bh8*)&sB[(wn + t * 16 + l16) * 32 + quad * 8];
    }
#pragma unroll
    for (int i = 0; i < 4; i++)
#pragma unroll
      for (int j = 0; j < 4; j++) acc[i][j] = MFMA16(aF[i], bF[j], acc[i][j]);
  }

#pragma unroll
  for (int i = 0; i < 4; i++)
#pragma unroll
    for (int j = 0; j < 4; j++)
#pragma unroll
      for (int r = 0; r < 4; r++) {
        int row = bm + wm + i * 16 + quad * 4 + r;
        int col = bn + wn + j * 16 + l16;
        store_c(C, (size_t)row * N + col, acc[i][j][r]);
      }
}

// ---------------- RoPE in-place on qkv[4096][6144] (bf16) ----------------
__global__ __launch_bounds__(256) void rope_kernel(u16* __restrict__ qkv, const int* __restrict__ pos) {
  __shared__ float cb[64], sb[64];
  const int t = blockIdx.x;
  const int p = pos[t];
  if (threadIdx.x < 64) {
    int j = threadIdx.x;
    float ang = (float)p * exp2f(-0.20762050593046f * (float)j);
    cb[j] = cosf(ang);
    sb[j] = sinf(ang);
  }
  __syncthreads();
  u16* row = qkv + (size_t)t * 6144;
  for (int i = threadIdx.x; i < 2560; i += 256) {
    int head = i >> 6, j = i & 63;
    int off = (head < 32) ? head * 128 : 4096 + (head - 32) * 128;
    float c = cb[j], s = sb[j];
    float x1 = bf2f(row[off + j]);
    float x2 = bf2f(row[off + 64 + j]);
    row[off + j] = f2bf(x1 * c - x2 * s);
    row[off + 64 + j] = f2bf(x2 * c + x1 * s);
  }
}

// ---------------- Fused causal GQA flash attention ----------------
// Br=128 (4 waves x 32 rows), Bc=64, D=128. grid = (16, 64). bf16 in/out (ws).
// LDS: sK 17408B + sU 18432B (sV staging ALIASED with per-wave sP -- lifetimes are
// disjoint: sV lives staging->transpose (B2..B3), sP lives inside compute (after B3);
// next-iter B1 fences compute reads before restaging) + sVT 18432B = 54272B
// -> 3 blocks/CU (was 71680B -> 2 blocks/CU). VGPR=152 allows 3 waves/SIMD.
__global__ __launch_bounds__(256) void attn_fused(const u16* __restrict__ qkv,
                                                  u16* __restrict__ aout) {
  constexpr int LDQ = 6144;
  constexpr int LDK = 136;  // K/V staging stride (pad 8, keeps 16B row alignment)
  constexpr int LDV = 72;   // sVT/sP stride
  const int qt = blockIdx.x, bh = blockIdx.y;
  const int bb = bh >> 5, h = bh & 31, kvh = h >> 2;
  const u16* Qb = qkv + (size_t)bb * 2048 * LDQ + h * 128;
  const u16* Kb = qkv + (size_t)bb * 2048 * LDQ + 4096 + kvh * 128;
  const u16* Vb = Kb + 1024;  // v section at 5120
  u16* Ob = aout + (size_t)bb * 2048 * 4096 + h * 128;

  __shared__ u16 sK[64 * LDK];        // [k][d]
  __shared__ u16 sU[4 * 32 * LDV];    // sV [64][LDK] (8704 elems) ALIAS sP[4][32*LDV]
  __shared__ u16 sVT[128 * LDV];      // [d][k]
  u16* sV = sU;

  const int tid = threadIdx.x;
  const int wave = tid >> 6, lane = tid & 63;
  const int quad = lane >> 4, l16 = lane & 15;

  bh8 qf[2][4];
#pragma unroll
  for (int mt = 0; mt < 2; mt++) {
    int row = qt * 128 + wave * 32 + mt * 16 + l16;
#pragma unroll
    for (int kb = 0; kb < 4; kb++)
      qf[mt][kb] = *(const bh8*)(Qb + (size_t)row * LDQ + kb * 32 + quad * 8);
  }

  f4 zero4 = {0.f, 0.f, 0.f, 0.f};
  f4 oacc[2][8];
#pragma unroll
  for (int mt = 0; mt < 2; mt++)
#pragma unroll
    for (int n = 0; n < 8; n++) oacc[mt][n] = zero4;
  float mI[2][4], lI[2][4];
#pragma unroll
  for (int mt = 0; mt < 2; mt++)
#pragma unroll
    for (int r = 0; r < 4; r++) { mI[mt][r] = -1e30f; lI[mt][r] = 0.f; }

  const float SCALE = 0.08838834764831845f;  // 1/sqrt(128)
  const float L2E = 1.4426950408889634f;
  const int iters = 2 * qt + 2;
  const int wave_maxrow = qt * 128 + wave * 32 + 31;

  for (int kt = 0; kt < iters; kt++) {
    __syncthreads();  // B1: prior iter's LDS reads (incl. sP reads) complete
#pragma unroll
    for (int rr = 0; rr < 4; rr++) {
      int c = rr * 256 + tid;        // 0..1023
      int row = c >> 4, col8 = c & 15;
      const size_t goff = (size_t)(kt * 64 + row) * LDQ + col8 * 8;
      bh8 kv = *(const bh8*)(Kb + goff);
      *(bh8*)&sK[row * LDK + col8 * 8] = kv;
      bh8 vv = *(const bh8*)(Vb + goff);
      *(bh8*)&sV[row * LDK + col8 * 8] = vv;
    }
    __syncthreads();  // B2: staging visible
    {  // transpose V [64][128] -> sVT [128][LDV]
      int d = tid & 127, khalf = tid >> 7;
#pragma unroll
      for (int seg = 0; seg < 4; seg++) {
        int k0 = khalf * 8 + seg * 16;
        bh8 tv;
#pragma unroll
        for (int j = 0; j < 8; j++) tv[j] = (short)sV[(k0 + j) * LDK + d];
        *(bh8*)&sVT[d * LDV + k0] = tv;
      }
    }
    __syncthreads();  // B3: transpose visible; sV dead from here -> sP may reuse

    if (kt * 64 <= wave_maxrow) {  // skip fully-masked tiles for this wave
      // ---- QK^T ----
      f4 sc[2][4];
#pragma unroll
      for (int mt = 0; mt < 2; mt++)
#pragma unroll
        for (int nt = 0; nt < 4; nt++) sc[mt][nt] = zero4;
#pragma unroll
      for (int nt = 0; nt < 4; nt++) {
        const int krow = nt * 16 + l16;
#pragma unroll
        for (int kb = 0; kb < 4; kb++) {
          bh8 kf = *(const bh8*)&sK[krow * LDK + (kb * 4 + quad) * 8];
          sc[0][nt] = MFMA16(qf[0][kb], kf, sc[0][nt]);
          sc[1][nt] = MFMA16(qf[1][kb], kf, sc[1][nt]);
        }
      }
      // ---- online softmax ----
      float alpha[2][4];
#pragma unroll
      for (int mt = 0; mt < 2; mt++)
#pragma unroll
        for (int r = 0; r < 4; r++) {
          int row = qt * 128 + wave * 32 + mt * 16 + quad * 4 + r;
          float tm = -1e30f;
#pragma unroll
          for (int nt = 0; nt < 4; nt++) {
            int col = kt * 64 + nt * 16 + l16;
            float v = (col <= row) ? sc[mt][nt][r] * SCALE : -1e30f;
            sc[mt][nt][r] = v;
            tm = fmaxf(tm, v);
          }
          tm = rmax16(tm);
          float mn = fmaxf(mI[mt][r], tm);
          alpha[mt][r] = exp2f((mI[mt][r] - mn) * L2E);
          float s = 0.f;
#pragma unroll
          for (int nt = 0; nt < 4; nt++) {
            float p = exp2f((sc[mt][nt][r] - mn) * L2E);
            sc[mt][nt][r] = p;
            s += p;
          }
          s = rsum16(s);
          lI[mt][r] = lI[mt][r] * alpha[mt][r] + s;
          mI[mt][r] = mn;
        }
#pragma unroll
      for (int mt = 0; mt < 2; mt++)
#pragma unroll
        for (int n = 0; n < 8; n++)
#pragma unroll
          for (int r = 0; r < 4; r++) oacc[mt][n][r] *= alpha[mt][r];
      // ---- P: C-layout -> LDS bf16 -> A-layout (m120 pattern), sP aliases sV ----
      u16* sPw = &sU[wave * 32 * LDV];
#pragma unroll
      for (int mt = 0; mt < 2; mt++)
#pragma unroll
        for (int nt = 0; nt < 4; nt++)
#pragma unroll
          for (int r = 0; r < 4; r++)
            sPw[(mt * 16 + quad * 4 + r) * LDV + nt * 16 + l16] = f2bf(sc[mt][nt][r]);
      bh8 pf[2][2];
#pragma unroll
      for (int mt = 0; mt < 2; mt++)
#pragma unroll
        for (int kb2 = 0; kb2 < 2; kb2++)
          pf[mt][kb2] = *(const bh8*)&sPw[(mt * 16 + l16) * LDV + kb2 * 32 + quad * 8];
      // ---- P @ V ----
#pragma unroll
      for (int n = 0; n < 8; n++) {
#pragma unroll
        for (int kb2 = 0; kb2 < 2; kb2++) {
          bh8 vf = *(const bh8*)&sVT[(n * 16 + l16) * LDV + kb2 * 32 + quad * 8];
          oacc[0][n] = MFMA16(pf[0][kb2], vf, oacc[0][n]);
          oacc[1][n] = MFMA16(pf[1][kb2], vf, oacc[1][n]);
        }
      }
    }
  }

  // epilogue: O / l, write bf16 [token][h*128 + d]
#pragma unroll
  for (int mt = 0; mt < 2; mt++) {
    float inv[4];
#pragma unroll
    for (int r = 0; r < 4; r++) inv[r] = 1.0f / lI[mt][r];
#pragma unroll
    for (int n = 0; n < 8; n++)
#pragma unroll
      for (int r = 0; r < 4; r++) {
        int row = qt * 128 + wave * 32 + mt * 16 + quad * 4 + r;
        Ob[(size_t)row * 4096 + n * 16 + l16] = f2bf(oacc[mt][n][r] * inv[r]);
      }
  }
}

extern "C" void kernel_launch(void* const* d_in, const int* in_sizes, int n_in,
                              void* d_out, int out_size, void* d_ws, size_t ws_size,
                              hipStream_t stream) {
  const float* hidden = (const float*)d_in[0];   // fp32 [2,2048,4096]
  const int*   pos    = (const int*)d_in[1];     // int32 [2,2048]
  const float* w_qkv  = (const float*)d_in[2];   // fp32 [6144,4096]
  const float* w_o    = (const float*)d_in[3];   // fp32 [4096,4096]
  float* out = (float*)d_out;                    // fp32 [2,2048,4096]

  u16* qkv  = (u16*)d_ws;                                  // [4096][6144] @ 0
  u16* aout = (u16*)((char*)d_ws + (size_t)50331648);      // [4096][4096] @ 50.3MB

  if (ws_size >= (size_t)134217728) {
    // fast path: bf16 copies + global_load_lds GEMMs
    u16* hb  = (u16*)((char*)d_ws + (size_t)50331648);     // aliases aout (disjoint life)
    u16* wqb = (u16*)((char*)d_ws + (size_t)83886080);
    u16* wob = (u16*)((char*)d_ws + (size_t)83886080);     // reuses wqb after gemm1

    f32_to_bf16<<<dim3(1024), 256, 0, stream>>>(hidden, hb, 2097152);   // 16.8M elems
    f32_to_bf16<<<dim3(1024), 256, 0, stream>>>(w_qkv, wqb, 3145728);   // 25.2M elems
    gemm_bt_lds<u16><<<dim3(48, 32), 256, 0, stream>>>(hb, wqb, qkv, 4096, 6144, 4096);
    f32_to_bf16<<<dim3(1024), 256, 0, stream>>>(w_o, wob, 2097152);     // wqb dead now
    rope_kernel<<<dim3(4096), 256, 0, stream>>>(qkv, pos);
    attn_fused<<<dim3(16, 64), 256, 0, stream>>>(qkv, aout);            // hb dead now
    gemm_bt_lds<float><<<dim3(32, 32), 256, 0, stream>>>(aout, wob, out, 4096, 4096, 4096);
  } else {
    // fallback: previous verified path (84MB ws)
    gemm_bt<float, float, u16><<<dim3(48, 32), 256, 0, stream>>>(
        hidden, w_qkv, qkv, 4096, 6144, 4096);
    rope_kernel<<<dim3(4096), 256, 0, stream>>>(qkv, pos);
    attn_fused<<<dim3(16, 64), 256, 0, stream>>>(qkv, aout);
    gemm_bt<u16, float, float><<<dim3(32, 32), 256, 0, stream>>>(
        aout, w_o, out, 4096, 4096, 4096);
  }
}